// Round 4
// baseline (7156.498 us; speedup 1.0000x reference)
//
#include <hip/hip_runtime.h>
#include <cstdint>
#include <cstddef>

#define HW_NRAYS 16384
#define NSAMP    (1 << 21)
#define NLEV     12
#define TSZ      (1 << 19)
#define TMASK    (TSZ - 1)
#define DIN      24
#define HDIM     32
#define WS_TAB_QWORDS (NLEV * TSZ)
#define WS_TAB_BYTES  ((size_t)WS_TAB_QWORDS * 8)
#define PRIME1 2654435761u
#define PRIME2 805459861u

__device__ __forceinline__ float clamp01f(float v) { return fminf(fmaxf(v, 0.f), 1.f); }

__device__ __forceinline__ uint32_t rne_bf16_lo(uint32_t u) {
    // round-to-nearest-even f32 -> bf16, result in low 16 bits
    return (u + 0x7fffu + ((u >> 16) & 1u)) >> 16;
}
__device__ __forceinline__ uint32_t pk_bf16x2(float lo, float hi) {
    return rne_bf16_lo(__float_as_uint(lo)) | (rne_bf16_lo(__float_as_uint(hi)) << 16);
}
__device__ __forceinline__ float bf_lo(uint32_t v) { return __uint_as_float(v << 16); }
__device__ __forceinline__ float bf_hi(uint32_t v) { return __uint_as_float(v & 0xffff0000u); }

// Pack (d0,d1,c0,c1) per hash entry into 4x bf16 (8 bytes): one gather feeds both MLPs.
__global__ __launch_bounds__(256)
void ngp_pack_tables(const float2* __restrict__ tab_d,
                     const float2* __restrict__ tab_c,
                     uint2* __restrict__ ws_tab)
{
    const int stride = gridDim.x * blockDim.x;
    for (int i = blockIdx.x * blockDim.x + threadIdx.x; i < WS_TAB_QWORDS; i += stride) {
        const float2 d = tab_d[i];
        const float2 c = tab_c[i];
        const uint32_t w0 = rne_bf16_lo(__float_as_uint(d.x)) | (rne_bf16_lo(__float_as_uint(d.y)) << 16);
        const uint32_t w1 = rne_bf16_lo(__float_as_uint(c.x)) | (rne_bf16_lo(__float_as_uint(c.y)) << 16);
        ws_tab[i] = make_uint2(w0, w1);
    }
}

// ---------------- fast path: packed bf16 table, feature-accumulate, chunked MLP ----------------
__global__ __attribute__((amdgpu_flat_work_group_size(64, 64), amdgpu_waves_per_eu(4, 4)))
void ngp_render_fast(const float* __restrict__ rays_o,
                     const float* __restrict__ rays_d,
                     const float* __restrict__ t_starts,
                     const float* __restrict__ t_ends,
                     const int*   __restrict__ ray_idx,
                     const uint2* __restrict__ ws_tab,
                     const float* __restrict__ w_d1,
                     const float* __restrict__ w_d2,
                     const float* __restrict__ w_c1,
                     const float* __restrict__ w_c2,
                     float* __restrict__ out)
{
    __shared__ __align__(16) float s_wd1[DIN * HDIM];
    __shared__ __align__(16) float s_wc1[DIN * HDIM];
    __shared__ __align__(16) float s_wd2[HDIM];
    __shared__ __align__(16) float s_wc2[HDIM * 3];

    const int lane = threadIdx.x;
    for (int i = lane; i < DIN * HDIM; i += 64) { s_wd1[i] = w_d1[i]; s_wc1[i] = w_c1[i]; }
    if (lane < HDIM) s_wd2[lane] = w_d2[lane];
    for (int i = lane; i < HDIM * 3; i += 64) s_wc2[i] = w_c2[i];
    __syncthreads();

    const int r = blockIdx.x;

    // lower_bound(ray_idx, r) / lower_bound(ray_idx, r+1) on sorted array
    int lo = 0, hi = NSAMP;
    while (lo < hi) { int m = (lo + hi) >> 1; if (ray_idx[m] < r) lo = m + 1; else hi = m; }
    const int start = lo;
    hi = NSAMP;
    while (lo < hi) { int m = (lo + hi) >> 1; if (ray_idx[m] <= r) lo = m + 1; else hi = m; }
    const int end = lo;

    const float ox = rays_o[3 * r + 0], oy = rays_o[3 * r + 1], oz = rays_o[3 * r + 2];
    const float dx = rays_d[3 * r + 0], dy = rays_d[3 * r + 1], dz = rays_d[3 * r + 2];

    float carry = 0.f, accw = 0.f, cr = 0.f, cg = 0.f, cb = 0.f;

    for (int base = start; base < end; base += 64) {
        const int i = base + lane;
        const bool valid = i < end;
        float sv = 0.f, R = 0.f, G = 0.f, B = 0.f;
        if (valid) {
            const float ts = t_starts[i], te = t_ends[i];
            const float tm = 0.5f * (ts + te);
            const float x01x = clamp01f((ox + dx * tm + 1.f) * 0.5f);
            const float x01y = clamp01f((oy + dy * tm + 1.f) * 0.5f);
            const float x01z = clamp01f((oz + dz * tm + 1.f) * 0.5f);

            // ---- hash-grid features: 4 per level, packed to bf16x2 immediately ----
            uint32_t fpkD[NLEV], fpkC[NLEV];
            #pragma unroll
            for (int l = 0; l < NLEV; ++l) {
                const float res1 = (float)((16 << l) - 1);
                const float px = x01x * res1, py = x01y * res1, pz = x01z * res1;
                const float fxf = floorf(px), fyf = floorf(py), fzf = floorf(pz);
                const uint32_t ix = (uint32_t)fxf, iy = (uint32_t)fyf, iz = (uint32_t)fzf;
                const float fx = px - fxf, fy = py - fyf, fz = pz - fzf;
                const uint32_t hx0 = ix, hx1 = ix + 1u;
                const uint32_t hy0 = iy * PRIME1, hy1 = hy0 + PRIME1;
                const uint32_t hz0 = iz * PRIME2, hz1 = hz0 + PRIME2;
                const uint2* tl = ws_tab + (size_t)l * TSZ;
                float a0 = 0.f, a1 = 0.f, b0 = 0.f, b1 = 0.f;
                #pragma unroll
                for (int c = 0; c < 8; ++c) {
                    const uint32_t h = ((c & 1) ? hx1 : hx0) ^ ((c & 2) ? hy1 : hy0) ^ ((c & 4) ? hz1 : hz0);
                    const float w = ((c & 1) ? fx : 1.f - fx) * ((c & 2) ? fy : 1.f - fy) * ((c & 4) ? fz : 1.f - fz);
                    const uint2 v = tl[h & TMASK];
                    a0 += w * bf_lo(v.x); a1 += w * bf_hi(v.x);
                    b0 += w * bf_lo(v.y); b1 += w * bf_hi(v.y);
                }
                fpkD[l] = pk_bf16x2(a0, a1);
                fpkC[l] = pk_bf16x2(b0, b1);
            }

            // ---- density MLP 24->32(relu)->1, hidden processed in 8-wide chunks ----
            float sD = 0.f;
            #pragma unroll
            for (int jc = 0; jc < 4; ++jc) {
                float h[8];
                #pragma unroll
                for (int j = 0; j < 8; ++j) h[j] = 0.f;
                #pragma unroll
                for (int l = 0; l < NLEV; ++l) {
                    const float d0 = bf_lo(fpkD[l]);
                    const float d1 = bf_hi(fpkD[l]);
                    const float* row0 = s_wd1 + (2 * l + 0) * HDIM + jc * 8;
                    const float* row1 = s_wd1 + (2 * l + 1) * HDIM + jc * 8;
                    #pragma unroll
                    for (int j = 0; j < 8; j += 4) {
                        const float4 a = *(const float4*)(row0 + j);
                        const float4 b = *(const float4*)(row1 + j);
                        h[j + 0] += d0 * a.x + d1 * b.x;
                        h[j + 1] += d0 * a.y + d1 * b.y;
                        h[j + 2] += d0 * a.z + d1 * b.z;
                        h[j + 3] += d0 * a.w + d1 * b.w;
                    }
                }
                #pragma unroll
                for (int j = 0; j < 8; ++j)
                    sD += fmaxf(h[j], 0.f) * s_wd2[jc * 8 + j];
            }
            sv = __expf(sD) * (te - ts);

            // ---- color MLP 24->32(relu)->3 ----
            float pr = 0.f, pg = 0.f, pb = 0.f;
            #pragma unroll
            for (int jc = 0; jc < 4; ++jc) {
                float h[8];
                #pragma unroll
                for (int j = 0; j < 8; ++j) h[j] = 0.f;
                #pragma unroll
                for (int l = 0; l < NLEV; ++l) {
                    const float c0 = bf_lo(fpkC[l]);
                    const float c1 = bf_hi(fpkC[l]);
                    const float* row0 = s_wc1 + (2 * l + 0) * HDIM + jc * 8;
                    const float* row1 = s_wc1 + (2 * l + 1) * HDIM + jc * 8;
                    #pragma unroll
                    for (int j = 0; j < 8; j += 4) {
                        const float4 a = *(const float4*)(row0 + j);
                        const float4 b = *(const float4*)(row1 + j);
                        h[j + 0] += c0 * a.x + c1 * b.x;
                        h[j + 1] += c0 * a.y + c1 * b.y;
                        h[j + 2] += c0 * a.z + c1 * b.z;
                        h[j + 3] += c0 * a.w + c1 * b.w;
                    }
                }
                #pragma unroll
                for (int j = 0; j < 8; ++j) {
                    const float hj = fmaxf(h[j], 0.f);
                    pr += hj * s_wc2[3 * (jc * 8 + j) + 0];
                    pg += hj * s_wc2[3 * (jc * 8 + j) + 1];
                    pb += hj * s_wc2[3 * (jc * 8 + j) + 2];
                }
            }
            R = 1.f / (1.f + __expf(-pr));
            G = 1.f / (1.f + __expf(-pg));
            B = 1.f / (1.f + __expf(-pb));
        }

        // wave-wide inclusive scan of sv (64 lanes)
        float incl = sv;
        #pragma unroll
        for (int off = 1; off < 64; off <<= 1) {
            float t = __shfl_up(incl, off);
            if (lane >= off) incl += t;
        }
        const float e = carry + (incl - sv);      // exclusive cumsum within ray
        const float w = valid ? (1.f - __expf(-sv)) * __expf(-e) : 0.f;
        accw += w; cr += w * R; cg += w * G; cb += w * B;
        carry += __shfl(incl, 63);
    }

    #pragma unroll
    for (int off = 32; off > 0; off >>= 1) {
        accw += __shfl_down(accw, off);
        cr   += __shfl_down(cr, off);
        cg   += __shfl_down(cg, off);
        cb   += __shfl_down(cb, off);
    }

    if (lane == 0) {
        const float bgw = 1.f - accw;   // BG_COLOR = 1.0
        out[0 * HW_NRAYS + r] = clamp01f(cr + bgw);
        out[1 * HW_NRAYS + r] = clamp01f(cg + bgw);
        out[2 * HW_NRAYS + r] = clamp01f(cb + bgw);
        out[3 * HW_NRAYS + r] = clamp01f(accw);
    }
}

// ---------------- fallback (no workspace): f32 tables, rank-1 updates ----------------
__global__ __launch_bounds__(64, 4)
void ngp_render_ref(const float* __restrict__ rays_o,
                    const float* __restrict__ rays_d,
                    const float* __restrict__ t_starts,
                    const float* __restrict__ t_ends,
                    const int*   __restrict__ ray_idx,
                    const float* __restrict__ tab_d,
                    const float* __restrict__ tab_c,
                    const float* __restrict__ w_d1,
                    const float* __restrict__ w_d2,
                    const float* __restrict__ w_c1,
                    const float* __restrict__ w_c2,
                    float* __restrict__ out)
{
    __shared__ __align__(16) float s_wd1[DIN * HDIM];
    __shared__ __align__(16) float s_wc1[DIN * HDIM];
    __shared__ __align__(16) float s_wd2[HDIM];
    __shared__ __align__(16) float s_wc2[HDIM * 3];

    const int lane = threadIdx.x;
    for (int i = lane; i < DIN * HDIM; i += 64) { s_wd1[i] = w_d1[i]; s_wc1[i] = w_c1[i]; }
    if (lane < HDIM) s_wd2[lane] = w_d2[lane];
    for (int i = lane; i < HDIM * 3; i += 64) s_wc2[i] = w_c2[i];
    __syncthreads();

    const int r = blockIdx.x;
    int lo = 0, hi = NSAMP;
    while (lo < hi) { int m = (lo + hi) >> 1; if (ray_idx[m] < r) lo = m + 1; else hi = m; }
    const int start = lo;
    hi = NSAMP;
    while (lo < hi) { int m = (lo + hi) >> 1; if (ray_idx[m] <= r) lo = m + 1; else hi = m; }
    const int end = lo;

    const float ox = rays_o[3 * r + 0], oy = rays_o[3 * r + 1], oz = rays_o[3 * r + 2];
    const float dx = rays_d[3 * r + 0], dy = rays_d[3 * r + 1], dz = rays_d[3 * r + 2];

    float carry = 0.f, accw = 0.f, cr = 0.f, cg = 0.f, cb = 0.f;

    for (int base = start; base < end; base += 64) {
        const int i = base + lane;
        const bool valid = i < end;
        float sv = 0.f, R = 0.f, G = 0.f, B = 0.f;
        if (valid) {
            const float ts = t_starts[i], te = t_ends[i];
            const float tm = 0.5f * (ts + te);
            const float x01x = clamp01f((ox + dx * tm + 1.f) * 0.5f);
            const float x01y = clamp01f((oy + dy * tm + 1.f) * 0.5f);
            const float x01z = clamp01f((oz + dz * tm + 1.f) * 0.5f);

            float hbD[HDIM], hbC[HDIM];
            #pragma unroll
            for (int j = 0; j < HDIM; ++j) { hbD[j] = 0.f; hbC[j] = 0.f; }

            #pragma unroll 1
            for (int l = 0; l < NLEV; ++l) {
                const float res1 = (float)((16 << l) - 1);
                const float px = x01x * res1, py = x01y * res1, pz = x01z * res1;
                const float fxf = floorf(px), fyf = floorf(py), fzf = floorf(pz);
                const uint32_t ix = (uint32_t)fxf, iy = (uint32_t)fyf, iz = (uint32_t)fzf;
                const float fx = px - fxf, fy = py - fyf, fz = pz - fzf;
                const uint32_t hx0 = ix, hx1 = ix + 1u;
                const uint32_t hy0 = iy * PRIME1, hy1 = hy0 + PRIME1;
                const uint32_t hz0 = iz * PRIME2, hz1 = hz0 + PRIME2;
                const float* td = tab_d + (size_t)l * (TSZ * 2);
                const float* tc = tab_c + (size_t)l * (TSZ * 2);
                float a0 = 0.f, a1 = 0.f, b0 = 0.f, b1 = 0.f;
                #pragma unroll
                for (int c = 0; c < 8; ++c) {
                    const uint32_t h = ((c & 1) ? hx1 : hx0) ^ ((c & 2) ? hy1 : hy0) ^ ((c & 4) ? hz1 : hz0);
                    const float w = ((c & 1) ? fx : 1.f - fx) * ((c & 2) ? fy : 1.f - fy) * ((c & 4) ? fz : 1.f - fz);
                    const float2 vd = *(const float2*)(td + (size_t)((h & TMASK) * 2u));
                    const float2 vc = *(const float2*)(tc + (size_t)((h & TMASK) * 2u));
                    a0 += w * vd.x; a1 += w * vd.y; b0 += w * vc.x; b1 += w * vc.y;
                }
                #pragma unroll
                for (int j = 0; j < HDIM; j += 4) {
                    const float4 u0 = *(const float4*)(s_wd1 + (2 * l + 0) * HDIM + j);
                    const float4 u1 = *(const float4*)(s_wd1 + (2 * l + 1) * HDIM + j);
                    hbD[j + 0] += a0 * u0.x + a1 * u1.x;
                    hbD[j + 1] += a0 * u0.y + a1 * u1.y;
                    hbD[j + 2] += a0 * u0.z + a1 * u1.z;
                    hbD[j + 3] += a0 * u0.w + a1 * u1.w;
                    const float4 v0 = *(const float4*)(s_wc1 + (2 * l + 0) * HDIM + j);
                    const float4 v1 = *(const float4*)(s_wc1 + (2 * l + 1) * HDIM + j);
                    hbC[j + 0] += b0 * v0.x + b1 * v1.x;
                    hbC[j + 1] += b0 * v0.y + b1 * v1.y;
                    hbC[j + 2] += b0 * v0.z + b1 * v1.z;
                    hbC[j + 3] += b0 * v0.w + b1 * v1.w;
                }
            }

            float dotv = 0.f;
            #pragma unroll
            for (int j = 0; j < HDIM; ++j) dotv += fmaxf(hbD[j], 0.f) * s_wd2[j];
            sv = __expf(dotv) * (te - ts);

            float pr = 0.f, pg = 0.f, pb = 0.f;
            #pragma unroll
            for (int j = 0; j < HDIM; ++j) {
                const float hj = fmaxf(hbC[j], 0.f);
                pr += hj * s_wc2[3 * j + 0];
                pg += hj * s_wc2[3 * j + 1];
                pb += hj * s_wc2[3 * j + 2];
            }
            R = 1.f / (1.f + __expf(-pr));
            G = 1.f / (1.f + __expf(-pg));
            B = 1.f / (1.f + __expf(-pb));
        }

        float incl = sv;
        #pragma unroll
        for (int off = 1; off < 64; off <<= 1) {
            float t = __shfl_up(incl, off);
            if (lane >= off) incl += t;
        }
        const float e = carry + (incl - sv);
        const float w = valid ? (1.f - __expf(-sv)) * __expf(-e) : 0.f;
        accw += w; cr += w * R; cg += w * G; cb += w * B;
        carry += __shfl(incl, 63);
    }

    #pragma unroll
    for (int off = 32; off > 0; off >>= 1) {
        accw += __shfl_down(accw, off);
        cr   += __shfl_down(cr, off);
        cg   += __shfl_down(cg, off);
        cb   += __shfl_down(cb, off);
    }

    if (lane == 0) {
        const float bgw = 1.f - accw;
        out[0 * HW_NRAYS + r] = clamp01f(cr + bgw);
        out[1 * HW_NRAYS + r] = clamp01f(cg + bgw);
        out[2 * HW_NRAYS + r] = clamp01f(cb + bgw);
        out[3 * HW_NRAYS + r] = clamp01f(accw);
    }
}

extern "C" void kernel_launch(void* const* d_in, const int* in_sizes, int n_in,
                              void* d_out, int out_size, void* d_ws, size_t ws_size,
                              hipStream_t stream) {
    const float* rays_o        = (const float*)d_in[0];
    const float* rays_d        = (const float*)d_in[1];
    const float* t_starts      = (const float*)d_in[2];
    const float* t_ends        = (const float*)d_in[3];
    const int*   ray_indices   = (const int*)d_in[4];
    const float* table_density = (const float*)d_in[5];
    const float* table_color   = (const float*)d_in[6];
    const float* w_d1          = (const float*)d_in[7];
    const float* w_d2          = (const float*)d_in[8];
    const float* w_c1          = (const float*)d_in[9];
    const float* w_c2          = (const float*)d_in[10];
    float* outp = (float*)d_out;

    if (ws_size >= WS_TAB_BYTES) {
        uint2* ws_tab = (uint2*)d_ws;
        hipLaunchKernelGGL(ngp_pack_tables, dim3(1024), dim3(256), 0, stream,
                           (const float2*)table_density, (const float2*)table_color, ws_tab);
        hipLaunchKernelGGL(ngp_render_fast, dim3(HW_NRAYS), dim3(64), 0, stream,
                           rays_o, rays_d, t_starts, t_ends, ray_indices, ws_tab,
                           w_d1, w_d2, w_c1, w_c2, outp);
    } else {
        hipLaunchKernelGGL(ngp_render_ref, dim3(HW_NRAYS), dim3(64), 0, stream,
                           rays_o, rays_d, t_starts, t_ends, ray_indices,
                           table_density, table_color,
                           w_d1, w_d2, w_c1, w_c2, outp);
    }
}

// Round 5
// 1362.526 us; speedup vs baseline: 5.2524x; 5.2524x over previous
//
#include <hip/hip_runtime.h>
#include <hip/hip_fp16.h>
#include <cstdint>
#include <cstddef>

#define HW_NRAYS 16384
#define NSAMP    (1 << 21)
#define NLEV     12
#define TSZ      (1 << 19)
#define TMASK    (TSZ - 1)
#define DIN      24
#define HDIM     32
#define WS_TAB_QWORDS (NLEV * TSZ)
#define WS_TAB_BYTES  ((size_t)WS_TAB_QWORDS * 8)
#define PRIME1 2654435761u
#define PRIME2 805459861u

__device__ __forceinline__ float clamp01f(float v) { return fminf(fmaxf(v, 0.f), 1.f); }

__device__ __forceinline__ uint32_t rne_bf16_lo(uint32_t u) {
    return (u + 0x7fffu + ((u >> 16) & 1u)) >> 16;
}
__device__ __forceinline__ float bf_lo(uint32_t v) { return __uint_as_float(v << 16); }
__device__ __forceinline__ float bf_hi(uint32_t v) { return __uint_as_float(v & 0xffff0000u); }

// Pack (d0,d1,c0,c1) per hash entry into 4x bf16 (8 bytes): one gather feeds both MLPs.
__global__ __launch_bounds__(256)
void ngp_pack_tables(const float2* __restrict__ tab_d,
                     const float2* __restrict__ tab_c,
                     uint2* __restrict__ ws_tab)
{
    const int stride = gridDim.x * blockDim.x;
    for (int i = blockIdx.x * blockDim.x + threadIdx.x; i < WS_TAB_QWORDS; i += stride) {
        const float2 d = tab_d[i];
        const float2 c = tab_c[i];
        const uint32_t w0 = rne_bf16_lo(__float_as_uint(d.x)) | (rne_bf16_lo(__float_as_uint(d.y)) << 16);
        const uint32_t w1 = rne_bf16_lo(__float_as_uint(c.x)) | (rne_bf16_lo(__float_as_uint(c.y)) << 16);
        ws_tab[i] = make_uint2(w0, w1);
    }
}

union F4H2 { float4 f4; __half2 h2[4]; };

// ---------------- fast path ----------------
// 256 threads = 4 waves, one ray per wave. Packed bf16 table (1 gather feeds both
// branches). Hidden layers accumulated in packed fp16 (v_pk_fma_f16) -> 32 acc regs.
// Level loop unroll(1): small scheduling window, no spills (round-4 lesson).
__global__ __launch_bounds__(256, 4)
void ngp_render_fast(const float* __restrict__ rays_o,
                     const float* __restrict__ rays_d,
                     const float* __restrict__ t_starts,
                     const float* __restrict__ t_ends,
                     const int*   __restrict__ ray_idx,
                     const uint2* __restrict__ ws_tab,
                     const float* __restrict__ w_d1,
                     const float* __restrict__ w_d2,
                     const float* __restrict__ w_c1,
                     const float* __restrict__ w_c2,
                     float* __restrict__ out)
{
    // weights as half2: row k holds 16 half2 covering 32 hidden units
    __shared__ __align__(16) __half2 s_wd1h[DIN * 16];
    __shared__ __align__(16) __half2 s_wc1h[DIN * 16];
    __shared__ __align__(16) float   s_wd2[HDIM];
    __shared__ __align__(16) float   s_wc2[HDIM * 3];

    const int tid = threadIdx.x;
    for (int idx = tid; idx < DIN * 16; idx += 256) {
        const int k = idx >> 4, j2 = idx & 15;
        s_wd1h[idx] = __floats2half2_rn(w_d1[k * HDIM + 2 * j2], w_d1[k * HDIM + 2 * j2 + 1]);
        s_wc1h[idx] = __floats2half2_rn(w_c1[k * HDIM + 2 * j2], w_c1[k * HDIM + 2 * j2 + 1]);
    }
    if (tid < HDIM) s_wd2[tid] = w_d2[tid];
    if (tid < HDIM * 3) s_wc2[tid] = w_c2[tid];
    __syncthreads();

    const int lane = tid & 63;
    const int r = blockIdx.x * 4 + (tid >> 6);

    // lower_bound(ray_idx, r) / lower_bound(ray_idx, r+1) on sorted array
    int lo = 0, hi = NSAMP;
    while (lo < hi) { int m = (lo + hi) >> 1; if (ray_idx[m] < r) lo = m + 1; else hi = m; }
    const int start = lo;
    hi = NSAMP;
    while (lo < hi) { int m = (lo + hi) >> 1; if (ray_idx[m] <= r) lo = m + 1; else hi = m; }
    const int end = lo;

    const float ox = rays_o[3 * r + 0], oy = rays_o[3 * r + 1], oz = rays_o[3 * r + 2];
    const float dx = rays_d[3 * r + 0], dy = rays_d[3 * r + 1], dz = rays_d[3 * r + 2];

    float carry = 0.f, accw = 0.f, cr = 0.f, cg = 0.f, cb = 0.f;

    for (int base = start; base < end; base += 64) {
        const int i = base + lane;
        const bool valid = i < end;
        float sv = 0.f, R = 0.f, G = 0.f, B = 0.f;
        if (valid) {
            const float ts = t_starts[i], te = t_ends[i];
            const float tm = 0.5f * (ts + te);
            const float x01x = clamp01f((ox + dx * tm + 1.f) * 0.5f);
            const float x01y = clamp01f((oy + dy * tm + 1.f) * 0.5f);
            const float x01z = clamp01f((oz + dz * tm + 1.f) * 0.5f);

            __half2 hbD2[16], hbC2[16];
            #pragma unroll
            for (int j = 0; j < 16; ++j) {
                hbD2[j] = __floats2half2_rn(0.f, 0.f);
                hbC2[j] = __floats2half2_rn(0.f, 0.f);
            }

            #pragma unroll 1
            for (int l = 0; l < NLEV; ++l) {
                const float res1 = (float)((16 << l) - 1);
                const float px = x01x * res1, py = x01y * res1, pz = x01z * res1;
                const float fxf = floorf(px), fyf = floorf(py), fzf = floorf(pz);
                const uint32_t ix = (uint32_t)fxf, iy = (uint32_t)fyf, iz = (uint32_t)fzf;
                const float fx = px - fxf, fy = py - fyf, fz = pz - fzf;
                const uint32_t hx0 = ix, hx1 = ix + 1u;
                const uint32_t hy0 = iy * PRIME1, hy1 = hy0 + PRIME1;
                const uint32_t hz0 = iz * PRIME2, hz1 = hz0 + PRIME2;
                const uint2* tl = ws_tab + (size_t)l * TSZ;

                float a0 = 0.f, a1 = 0.f, b0 = 0.f, b1 = 0.f;
                #pragma unroll
                for (int c = 0; c < 8; ++c) {
                    const uint32_t h = ((c & 1) ? hx1 : hx0) ^ ((c & 2) ? hy1 : hy0) ^ ((c & 4) ? hz1 : hz0);
                    const float w = ((c & 1) ? fx : 1.f - fx) * ((c & 2) ? fy : 1.f - fy) * ((c & 4) ? fz : 1.f - fz);
                    const uint2 v = tl[h & TMASK];
                    a0 += w * bf_lo(v.x); a1 += w * bf_hi(v.x);
                    b0 += w * bf_lo(v.y); b1 += w * bf_hi(v.y);
                }

                const __half2 a0h = __float2half2_rn(a0);
                const __half2 a1h = __float2half2_rn(a1);
                const __half2 b0h = __float2half2_rn(b0);
                const __half2 b1h = __float2half2_rn(b1);

                const F4H2* wd0 = (const F4H2*)(s_wd1h + (2 * l + 0) * 16);
                const F4H2* wd1 = (const F4H2*)(s_wd1h + (2 * l + 1) * 16);
                const F4H2* wc0 = (const F4H2*)(s_wc1h + (2 * l + 0) * 16);
                const F4H2* wc1 = (const F4H2*)(s_wc1h + (2 * l + 1) * 16);
                #pragma unroll
                for (int q = 0; q < 4; ++q) {
                    F4H2 u0 = wd0[q], u1 = wd1[q];
                    F4H2 v0 = wc0[q], v1 = wc1[q];
                    #pragma unroll
                    for (int p = 0; p < 4; ++p) {
                        hbD2[q * 4 + p] = __hfma2(a0h, u0.h2[p], __hfma2(a1h, u1.h2[p], hbD2[q * 4 + p]));
                        hbC2[q * 4 + p] = __hfma2(b0h, v0.h2[p], __hfma2(b1h, v1.h2[p], hbC2[q * 4 + p]));
                    }
                }
            }

            // density head
            float sD = 0.f;
            #pragma unroll
            for (int j = 0; j < 16; ++j) {
                const float2 f = __half22float2(hbD2[j]);
                sD += fmaxf(f.x, 0.f) * s_wd2[2 * j] + fmaxf(f.y, 0.f) * s_wd2[2 * j + 1];
            }
            sv = __expf(sD) * (te - ts);

            // color head
            float pr = 0.f, pg = 0.f, pb = 0.f;
            #pragma unroll
            for (int j = 0; j < 16; ++j) {
                const float2 f = __half22float2(hbC2[j]);
                const float h0 = fmaxf(f.x, 0.f), h1 = fmaxf(f.y, 0.f);
                pr += h0 * s_wc2[3 * (2 * j) + 0] + h1 * s_wc2[3 * (2 * j + 1) + 0];
                pg += h0 * s_wc2[3 * (2 * j) + 1] + h1 * s_wc2[3 * (2 * j + 1) + 1];
                pb += h0 * s_wc2[3 * (2 * j) + 2] + h1 * s_wc2[3 * (2 * j + 1) + 2];
            }
            R = 1.f / (1.f + __expf(-pr));
            G = 1.f / (1.f + __expf(-pg));
            B = 1.f / (1.f + __expf(-pb));
        }

        // wave-wide inclusive scan of sv (64 lanes)
        float incl = sv;
        #pragma unroll
        for (int off = 1; off < 64; off <<= 1) {
            float t = __shfl_up(incl, off);
            if (lane >= off) incl += t;
        }
        const float e = carry + (incl - sv);      // exclusive cumsum within ray
        const float w = valid ? (1.f - __expf(-sv)) * __expf(-e) : 0.f;
        accw += w; cr += w * R; cg += w * G; cb += w * B;
        carry += __shfl(incl, 63);
    }

    #pragma unroll
    for (int off = 32; off > 0; off >>= 1) {
        accw += __shfl_down(accw, off);
        cr   += __shfl_down(cr, off);
        cg   += __shfl_down(cg, off);
        cb   += __shfl_down(cb, off);
    }

    if (lane == 0) {
        const float bgw = 1.f - accw;   // BG_COLOR = 1.0
        out[0 * HW_NRAYS + r] = clamp01f(cr + bgw);
        out[1 * HW_NRAYS + r] = clamp01f(cg + bgw);
        out[2 * HW_NRAYS + r] = clamp01f(cb + bgw);
        out[3 * HW_NRAYS + r] = clamp01f(accw);
    }
}

// ---------------- fallback (no workspace): round-3 proven kernel ----------------
__global__ __launch_bounds__(64, 4)
void ngp_render_ref(const float* __restrict__ rays_o,
                    const float* __restrict__ rays_d,
                    const float* __restrict__ t_starts,
                    const float* __restrict__ t_ends,
                    const int*   __restrict__ ray_idx,
                    const float* __restrict__ tab_d,
                    const float* __restrict__ tab_c,
                    const float* __restrict__ w_d1,
                    const float* __restrict__ w_d2,
                    const float* __restrict__ w_c1,
                    const float* __restrict__ w_c2,
                    float* __restrict__ out)
{
    __shared__ __align__(16) float s_wd1[DIN * HDIM];
    __shared__ __align__(16) float s_wc1[DIN * HDIM];
    __shared__ __align__(16) float s_wd2[HDIM];
    __shared__ __align__(16) float s_wc2[HDIM * 3];

    const int lane = threadIdx.x;
    for (int i = lane; i < DIN * HDIM; i += 64) { s_wd1[i] = w_d1[i]; s_wc1[i] = w_c1[i]; }
    if (lane < HDIM) s_wd2[lane] = w_d2[lane];
    for (int i = lane; i < HDIM * 3; i += 64) s_wc2[i] = w_c2[i];
    __syncthreads();

    const int r = blockIdx.x;
    int lo = 0, hi = NSAMP;
    while (lo < hi) { int m = (lo + hi) >> 1; if (ray_idx[m] < r) lo = m + 1; else hi = m; }
    const int start = lo;
    hi = NSAMP;
    while (lo < hi) { int m = (lo + hi) >> 1; if (ray_idx[m] <= r) lo = m + 1; else hi = m; }
    const int end = lo;

    const float ox = rays_o[3 * r + 0], oy = rays_o[3 * r + 1], oz = rays_o[3 * r + 2];
    const float dx = rays_d[3 * r + 0], dy = rays_d[3 * r + 1], dz = rays_d[3 * r + 2];

    float carry = 0.f, accw = 0.f, cr = 0.f, cg = 0.f, cb = 0.f;

    for (int base = start; base < end; base += 64) {
        const int i = base + lane;
        const bool valid = i < end;
        float sv = 0.f, R = 0.f, G = 0.f, B = 0.f;
        if (valid) {
            const float ts = t_starts[i], te = t_ends[i];
            const float tm = 0.5f * (ts + te);
            const float x01x = clamp01f((ox + dx * tm + 1.f) * 0.5f);
            const float x01y = clamp01f((oy + dy * tm + 1.f) * 0.5f);
            const float x01z = clamp01f((oz + dz * tm + 1.f) * 0.5f);

            float hbD[HDIM], hbC[HDIM];
            #pragma unroll
            for (int j = 0; j < HDIM; ++j) { hbD[j] = 0.f; hbC[j] = 0.f; }

            #pragma unroll 1
            for (int l = 0; l < NLEV; ++l) {
                const float res1 = (float)((16 << l) - 1);
                const float px = x01x * res1, py = x01y * res1, pz = x01z * res1;
                const float fxf = floorf(px), fyf = floorf(py), fzf = floorf(pz);
                const uint32_t ix = (uint32_t)fxf, iy = (uint32_t)fyf, iz = (uint32_t)fzf;
                const float fx = px - fxf, fy = py - fyf, fz = pz - fzf;
                const uint32_t hx0 = ix, hx1 = ix + 1u;
                const uint32_t hy0 = iy * PRIME1, hy1 = hy0 + PRIME1;
                const uint32_t hz0 = iz * PRIME2, hz1 = hz0 + PRIME2;
                const float* td = tab_d + (size_t)l * (TSZ * 2);
                const float* tc = tab_c + (size_t)l * (TSZ * 2);
                float a0 = 0.f, a1 = 0.f, b0 = 0.f, b1 = 0.f;
                #pragma unroll
                for (int c = 0; c < 8; ++c) {
                    const uint32_t h = ((c & 1) ? hx1 : hx0) ^ ((c & 2) ? hy1 : hy0) ^ ((c & 4) ? hz1 : hz0);
                    const float w = ((c & 1) ? fx : 1.f - fx) * ((c & 2) ? fy : 1.f - fy) * ((c & 4) ? fz : 1.f - fz);
                    const float2 vd = *(const float2*)(td + (size_t)((h & TMASK) * 2u));
                    const float2 vc = *(const float2*)(tc + (size_t)((h & TMASK) * 2u));
                    a0 += w * vd.x; a1 += w * vd.y; b0 += w * vc.x; b1 += w * vc.y;
                }
                #pragma unroll
                for (int j = 0; j < HDIM; j += 4) {
                    const float4 u0 = *(const float4*)(s_wd1 + (2 * l + 0) * HDIM + j);
                    const float4 u1 = *(const float4*)(s_wd1 + (2 * l + 1) * HDIM + j);
                    hbD[j + 0] += a0 * u0.x + a1 * u1.x;
                    hbD[j + 1] += a0 * u0.y + a1 * u1.y;
                    hbD[j + 2] += a0 * u0.z + a1 * u1.z;
                    hbD[j + 3] += a0 * u0.w + a1 * u1.w;
                    const float4 v0 = *(const float4*)(s_wc1 + (2 * l + 0) * HDIM + j);
                    const float4 v1 = *(const float4*)(s_wc1 + (2 * l + 1) * HDIM + j);
                    hbC[j + 0] += b0 * v0.x + b1 * v1.x;
                    hbC[j + 1] += b0 * v0.y + b1 * v1.y;
                    hbC[j + 2] += b0 * v0.z + b1 * v1.z;
                    hbC[j + 3] += b0 * v0.w + b1 * v1.w;
                }
            }

            float dotv = 0.f;
            #pragma unroll
            for (int j = 0; j < HDIM; ++j) dotv += fmaxf(hbD[j], 0.f) * s_wd2[j];
            sv = __expf(dotv) * (te - ts);

            float pr = 0.f, pg = 0.f, pb = 0.f;
            #pragma unroll
            for (int j = 0; j < HDIM; ++j) {
                const float hj = fmaxf(hbC[j], 0.f);
                pr += hj * s_wc2[3 * j + 0];
                pg += hj * s_wc2[3 * j + 1];
                pb += hj * s_wc2[3 * j + 2];
            }
            R = 1.f / (1.f + __expf(-pr));
            G = 1.f / (1.f + __expf(-pg));
            B = 1.f / (1.f + __expf(-pb));
        }

        float incl = sv;
        #pragma unroll
        for (int off = 1; off < 64; off <<= 1) {
            float t = __shfl_up(incl, off);
            if (lane >= off) incl += t;
        }
        const float e = carry + (incl - sv);
        const float w = valid ? (1.f - __expf(-sv)) * __expf(-e) : 0.f;
        accw += w; cr += w * R; cg += w * G; cb += w * B;
        carry += __shfl(incl, 63);
    }

    #pragma unroll
    for (int off = 32; off > 0; off >>= 1) {
        accw += __shfl_down(accw, off);
        cr   += __shfl_down(cr, off);
        cg   += __shfl_down(cg, off);
        cb   += __shfl_down(cb, off);
    }

    if (lane == 0) {
        const float bgw = 1.f - accw;
        out[0 * HW_NRAYS + r] = clamp01f(cr + bgw);
        out[1 * HW_NRAYS + r] = clamp01f(cg + bgw);
        out[2 * HW_NRAYS + r] = clamp01f(cb + bgw);
        out[3 * HW_NRAYS + r] = clamp01f(accw);
    }
}

extern "C" void kernel_launch(void* const* d_in, const int* in_sizes, int n_in,
                              void* d_out, int out_size, void* d_ws, size_t ws_size,
                              hipStream_t stream) {
    const float* rays_o        = (const float*)d_in[0];
    const float* rays_d        = (const float*)d_in[1];
    const float* t_starts      = (const float*)d_in[2];
    const float* t_ends        = (const float*)d_in[3];
    const int*   ray_indices   = (const int*)d_in[4];
    const float* table_density = (const float*)d_in[5];
    const float* table_color   = (const float*)d_in[6];
    const float* w_d1          = (const float*)d_in[7];
    const float* w_d2          = (const float*)d_in[8];
    const float* w_c1          = (const float*)d_in[9];
    const float* w_c2          = (const float*)d_in[10];
    float* outp = (float*)d_out;

    if (ws_size >= WS_TAB_BYTES) {
        uint2* ws_tab = (uint2*)d_ws;
        hipLaunchKernelGGL(ngp_pack_tables, dim3(1024), dim3(256), 0, stream,
                           (const float2*)table_density, (const float2*)table_color, ws_tab);
        hipLaunchKernelGGL(ngp_render_fast, dim3(HW_NRAYS / 4), dim3(256), 0, stream,
                           rays_o, rays_d, t_starts, t_ends, ray_indices, ws_tab,
                           w_d1, w_d2, w_c1, w_c2, outp);
    } else {
        hipLaunchKernelGGL(ngp_render_ref, dim3(HW_NRAYS), dim3(64), 0, stream,
                           rays_o, rays_d, t_starts, t_ends, ray_indices,
                           table_density, table_color,
                           w_d1, w_d2, w_c1, w_c2, outp);
    }
}

// Round 6
// 1236.895 us; speedup vs baseline: 5.7859x; 1.1016x over previous
//
#include <hip/hip_runtime.h>
#include <hip/hip_fp16.h>
#include <cstdint>
#include <cstddef>

#define HW_NRAYS 16384
#define NSAMP    (1 << 21)
#define NLEV     12
#define TSZ      (1 << 19)
#define TMASK    (TSZ - 1)
#define DIN      24
#define HDIM     32
#define WS_TAB_QWORDS (NLEV * TSZ)
#define WS_TAB_BYTES  ((size_t)WS_TAB_QWORDS * 8)
#define PRIME1 2654435761u
#define PRIME2 805459861u

__device__ __forceinline__ float clamp01f(float v) { return fminf(fmaxf(v, 0.f), 1.f); }

__device__ __forceinline__ uint32_t rne_bf16_lo(uint32_t u) {
    return (u + 0x7fffu + ((u >> 16) & 1u)) >> 16;
}
__device__ __forceinline__ float bf_lo(uint32_t v) { return __uint_as_float(v << 16); }
__device__ __forceinline__ float bf_hi(uint32_t v) { return __uint_as_float(v & 0xffff0000u); }

// Pack (d0,d1,c0,c1) per hash entry into 4x bf16 (8 bytes): one gather feeds both MLPs.
__global__ __launch_bounds__(256)
void ngp_pack_tables(const float2* __restrict__ tab_d,
                     const float2* __restrict__ tab_c,
                     uint2* __restrict__ ws_tab)
{
    const int stride = gridDim.x * blockDim.x;
    for (int i = blockIdx.x * blockDim.x + threadIdx.x; i < WS_TAB_QWORDS; i += stride) {
        const float2 d = tab_d[i];
        const float2 c = tab_c[i];
        const uint32_t w0 = rne_bf16_lo(__float_as_uint(d.x)) | (rne_bf16_lo(__float_as_uint(d.y)) << 16);
        const uint32_t w1 = rne_bf16_lo(__float_as_uint(c.x)) | (rne_bf16_lo(__float_as_uint(c.y)) << 16);
        ws_tab[i] = make_uint2(w0, w1);
    }
}

union H2U { __half2 h2; uint32_t u; };
union F4H2 { float4 f4; __half2 h2[4]; };

// ---------------- fast path ----------------
// 256 threads = 4 waves, one ray per wave. Packed bf16 table (1 gather feeds both
// branches). Two sub-phases per 64-sample batch, decoupled through a wave-private
// LDS feature buffer so gather-pressure and MLP-accumulator-pressure never
// overlap (round-5 lesson: their overlap is the spill source).
__global__ __launch_bounds__(256, 6)
void ngp_render_fast(const float* __restrict__ rays_o,
                     const float* __restrict__ rays_d,
                     const float* __restrict__ t_starts,
                     const float* __restrict__ t_ends,
                     const int*   __restrict__ ray_idx,
                     const uint2* __restrict__ ws_tab,
                     const float* __restrict__ w_d1,
                     const float* __restrict__ w_d2,
                     const float* __restrict__ w_c1,
                     const float* __restrict__ w_c2,
                     float* __restrict__ out)
{
    // weights as half2: row k holds 16 half2 covering 32 hidden units
    __shared__ __align__(16) __half2 s_wd1h[DIN * 16];
    __shared__ __align__(16) __half2 s_wc1h[DIN * 16];
    __shared__ __align__(16) float   s_wd2[HDIM];
    __shared__ __align__(16) float   s_wc2[HDIM * 3];
    // wave-private feature staging: [wave][level][lane] -> {half2(a0,a1), half2(b0,b1)}
    __shared__ __align__(16) uint2   s_feat[4 * NLEV * 64];

    const int tid = threadIdx.x;
    for (int idx = tid; idx < DIN * 16; idx += 256) {
        const int k = idx >> 4, j2 = idx & 15;
        s_wd1h[idx] = __floats2half2_rn(w_d1[k * HDIM + 2 * j2], w_d1[k * HDIM + 2 * j2 + 1]);
        s_wc1h[idx] = __floats2half2_rn(w_c1[k * HDIM + 2 * j2], w_c1[k * HDIM + 2 * j2 + 1]);
    }
    if (tid < HDIM) s_wd2[tid] = w_d2[tid];
    if (tid < HDIM * 3) s_wc2[tid] = w_c2[tid];
    __syncthreads();

    const int lane = tid & 63;
    const int wv = tid >> 6;
    const int r = blockIdx.x * 4 + wv;
    uint2* const feat = s_feat + wv * (NLEV * 64) + lane;   // index by + l*64

    // lower_bound(ray_idx, r) / lower_bound(ray_idx, r+1) on sorted array
    int lo = 0, hi = NSAMP;
    while (lo < hi) { int m = (lo + hi) >> 1; if (ray_idx[m] < r) lo = m + 1; else hi = m; }
    const int start = lo;
    hi = NSAMP;
    while (lo < hi) { int m = (lo + hi) >> 1; if (ray_idx[m] <= r) lo = m + 1; else hi = m; }
    const int end = lo;

    const float ox = rays_o[3 * r + 0], oy = rays_o[3 * r + 1], oz = rays_o[3 * r + 2];
    const float dx = rays_d[3 * r + 0], dy = rays_d[3 * r + 1], dz = rays_d[3 * r + 2];

    float carry = 0.f, accw = 0.f, cr = 0.f, cg = 0.f, cb = 0.f;

    for (int base = start; base < end; base += 64) {
        const int i = base + lane;
        const bool valid = i < end;
        float sv = 0.f, R = 0.f, G = 0.f, B = 0.f;
        if (valid) {
            const float ts = t_starts[i], te = t_ends[i];
            const float tm = 0.5f * (ts + te);
            const float x01x = clamp01f((ox + dx * tm + 1.f) * 0.5f);
            const float x01y = clamp01f((oy + dy * tm + 1.f) * 0.5f);
            const float x01z = clamp01f((oz + dz * tm + 1.f) * 0.5f);

            // ---------- phase 1: gather features, stage to LDS ----------
            #pragma unroll 1
            for (int l = 0; l < NLEV; ++l) {
                const float res1 = (float)((16 << l) - 1);
                const float px = x01x * res1, py = x01y * res1, pz = x01z * res1;
                const float fxf = floorf(px), fyf = floorf(py), fzf = floorf(pz);
                const uint32_t ix = (uint32_t)fxf, iy = (uint32_t)fyf, iz = (uint32_t)fzf;
                const float fx = px - fxf, fy = py - fyf, fz = pz - fzf;
                const uint32_t hx0 = ix, hx1 = ix + 1u;
                const uint32_t hy0 = iy * PRIME1, hy1 = hy0 + PRIME1;
                const uint32_t hz0 = iz * PRIME2, hz1 = hz0 + PRIME2;
                const uint2* tl = ws_tab + (size_t)l * TSZ;

                float a0 = 0.f, a1 = 0.f, b0 = 0.f, b1 = 0.f;
                #pragma unroll
                for (int c = 0; c < 8; ++c) {
                    const uint32_t h = ((c & 1) ? hx1 : hx0) ^ ((c & 2) ? hy1 : hy0) ^ ((c & 4) ? hz1 : hz0);
                    const float w = ((c & 1) ? fx : 1.f - fx) * ((c & 2) ? fy : 1.f - fy) * ((c & 4) ? fz : 1.f - fz);
                    const uint2 v = tl[h & TMASK];
                    a0 += w * bf_lo(v.x); a1 += w * bf_hi(v.x);
                    b0 += w * bf_lo(v.y); b1 += w * bf_hi(v.y);
                }
                H2U fD, fC;
                fD.h2 = __floats2half2_rn(a0, a1);
                fC.h2 = __floats2half2_rn(b0, b1);
                feat[l * 64] = make_uint2(fD.u, fC.u);
            }

            // ---------- phase 2: MLP from staged features (packed fp16) ----------
            __half2 hbD2[16], hbC2[16];
            #pragma unroll
            for (int j = 0; j < 16; ++j) {
                hbD2[j] = __floats2half2_rn(0.f, 0.f);
                hbC2[j] = __floats2half2_rn(0.f, 0.f);
            }

            #pragma unroll
            for (int l = 0; l < NLEV; ++l) {
                const uint2 fv = feat[l * 64];
                H2U fD, fC; fD.u = fv.x; fC.u = fv.y;
                const __half2 a0h = __low2half2(fD.h2);
                const __half2 a1h = __high2half2(fD.h2);
                const __half2 b0h = __low2half2(fC.h2);
                const __half2 b1h = __high2half2(fC.h2);

                const F4H2* wd0 = (const F4H2*)(s_wd1h + (2 * l + 0) * 16);
                const F4H2* wd1 = (const F4H2*)(s_wd1h + (2 * l + 1) * 16);
                const F4H2* wc0 = (const F4H2*)(s_wc1h + (2 * l + 0) * 16);
                const F4H2* wc1 = (const F4H2*)(s_wc1h + (2 * l + 1) * 16);
                #pragma unroll
                for (int q = 0; q < 4; ++q) {
                    F4H2 u0 = wd0[q], u1 = wd1[q];
                    F4H2 v0 = wc0[q], v1 = wc1[q];
                    #pragma unroll
                    for (int p = 0; p < 4; ++p) {
                        hbD2[q * 4 + p] = __hfma2(a0h, u0.h2[p], __hfma2(a1h, u1.h2[p], hbD2[q * 4 + p]));
                        hbC2[q * 4 + p] = __hfma2(b0h, v0.h2[p], __hfma2(b1h, v1.h2[p], hbC2[q * 4 + p]));
                    }
                }
            }

            // density head
            float sD = 0.f;
            #pragma unroll
            for (int j = 0; j < 16; ++j) {
                const float2 f = __half22float2(hbD2[j]);
                sD += fmaxf(f.x, 0.f) * s_wd2[2 * j] + fmaxf(f.y, 0.f) * s_wd2[2 * j + 1];
            }
            sv = __expf(sD) * (te - ts);

            // color head
            float pr = 0.f, pg = 0.f, pb = 0.f;
            #pragma unroll
            for (int j = 0; j < 16; ++j) {
                const float2 f = __half22float2(hbC2[j]);
                const float h0 = fmaxf(f.x, 0.f), h1 = fmaxf(f.y, 0.f);
                pr += h0 * s_wc2[3 * (2 * j) + 0] + h1 * s_wc2[3 * (2 * j + 1) + 0];
                pg += h0 * s_wc2[3 * (2 * j) + 1] + h1 * s_wc2[3 * (2 * j + 1) + 1];
                pb += h0 * s_wc2[3 * (2 * j) + 2] + h1 * s_wc2[3 * (2 * j + 1) + 2];
            }
            R = 1.f / (1.f + __expf(-pr));
            G = 1.f / (1.f + __expf(-pg));
            B = 1.f / (1.f + __expf(-pb));
        }

        // wave-wide inclusive scan of sv (64 lanes)
        float incl = sv;
        #pragma unroll
        for (int off = 1; off < 64; off <<= 1) {
            float t = __shfl_up(incl, off);
            if (lane >= off) incl += t;
        }
        const float e = carry + (incl - sv);      // exclusive cumsum within ray
        const float w = valid ? (1.f - __expf(-sv)) * __expf(-e) : 0.f;
        accw += w; cr += w * R; cg += w * G; cb += w * B;
        carry += __shfl(incl, 63);
    }

    #pragma unroll
    for (int off = 32; off > 0; off >>= 1) {
        accw += __shfl_down(accw, off);
        cr   += __shfl_down(cr, off);
        cg   += __shfl_down(cg, off);
        cb   += __shfl_down(cb, off);
    }

    if (lane == 0) {
        const float bgw = 1.f - accw;   // BG_COLOR = 1.0
        out[0 * HW_NRAYS + r] = clamp01f(cr + bgw);
        out[1 * HW_NRAYS + r] = clamp01f(cg + bgw);
        out[2 * HW_NRAYS + r] = clamp01f(cb + bgw);
        out[3 * HW_NRAYS + r] = clamp01f(accw);
    }
}

// ---------------- fallback (no workspace): round-3 proven kernel ----------------
__global__ __launch_bounds__(64, 4)
void ngp_render_ref(const float* __restrict__ rays_o,
                    const float* __restrict__ rays_d,
                    const float* __restrict__ t_starts,
                    const float* __restrict__ t_ends,
                    const int*   __restrict__ ray_idx,
                    const float* __restrict__ tab_d,
                    const float* __restrict__ tab_c,
                    const float* __restrict__ w_d1,
                    const float* __restrict__ w_d2,
                    const float* __restrict__ w_c1,
                    const float* __restrict__ w_c2,
                    float* __restrict__ out)
{
    __shared__ __align__(16) float s_wd1[DIN * HDIM];
    __shared__ __align__(16) float s_wc1[DIN * HDIM];
    __shared__ __align__(16) float s_wd2[HDIM];
    __shared__ __align__(16) float s_wc2[HDIM * 3];

    const int lane = threadIdx.x;
    for (int i = lane; i < DIN * HDIM; i += 64) { s_wd1[i] = w_d1[i]; s_wc1[i] = w_c1[i]; }
    if (lane < HDIM) s_wd2[lane] = w_d2[lane];
    for (int i = lane; i < HDIM * 3; i += 64) s_wc2[i] = w_c2[i];
    __syncthreads();

    const int r = blockIdx.x;
    int lo = 0, hi = NSAMP;
    while (lo < hi) { int m = (lo + hi) >> 1; if (ray_idx[m] < r) lo = m + 1; else hi = m; }
    const int start = lo;
    hi = NSAMP;
    while (lo < hi) { int m = (lo + hi) >> 1; if (ray_idx[m] <= r) lo = m + 1; else hi = m; }
    const int end = lo;

    const float ox = rays_o[3 * r + 0], oy = rays_o[3 * r + 1], oz = rays_o[3 * r + 2];
    const float dx = rays_d[3 * r + 0], dy = rays_d[3 * r + 1], dz = rays_d[3 * r + 2];

    float carry = 0.f, accw = 0.f, cr = 0.f, cg = 0.f, cb = 0.f;

    for (int base = start; base < end; base += 64) {
        const int i = base + lane;
        const bool valid = i < end;
        float sv = 0.f, R = 0.f, G = 0.f, B = 0.f;
        if (valid) {
            const float ts = t_starts[i], te = t_ends[i];
            const float tm = 0.5f * (ts + te);
            const float x01x = clamp01f((ox + dx * tm + 1.f) * 0.5f);
            const float x01y = clamp01f((oy + dy * tm + 1.f) * 0.5f);
            const float x01z = clamp01f((oz + dz * tm + 1.f) * 0.5f);

            float hbD[HDIM], hbC[HDIM];
            #pragma unroll
            for (int j = 0; j < HDIM; ++j) { hbD[j] = 0.f; hbC[j] = 0.f; }

            #pragma unroll 1
            for (int l = 0; l < NLEV; ++l) {
                const float res1 = (float)((16 << l) - 1);
                const float px = x01x * res1, py = x01y * res1, pz = x01z * res1;
                const float fxf = floorf(px), fyf = floorf(py), fzf = floorf(pz);
                const uint32_t ix = (uint32_t)fxf, iy = (uint32_t)fyf, iz = (uint32_t)fzf;
                const float fx = px - fxf, fy = py - fyf, fz = pz - fzf;
                const uint32_t hx0 = ix, hx1 = ix + 1u;
                const uint32_t hy0 = iy * PRIME1, hy1 = hy0 + PRIME1;
                const uint32_t hz0 = iz * PRIME2, hz1 = hz0 + PRIME2;
                const float* td = tab_d + (size_t)l * (TSZ * 2);
                const float* tc = tab_c + (size_t)l * (TSZ * 2);
                float a0 = 0.f, a1 = 0.f, b0 = 0.f, b1 = 0.f;
                #pragma unroll
                for (int c = 0; c < 8; ++c) {
                    const uint32_t h = ((c & 1) ? hx1 : hx0) ^ ((c & 2) ? hy1 : hy0) ^ ((c & 4) ? hz1 : hz0);
                    const float w = ((c & 1) ? fx : 1.f - fx) * ((c & 2) ? fy : 1.f - fy) * ((c & 4) ? fz : 1.f - fz);
                    const float2 vd = *(const float2*)(td + (size_t)((h & TMASK) * 2u));
                    const float2 vc = *(const float2*)(tc + (size_t)((h & TMASK) * 2u));
                    a0 += w * vd.x; a1 += w * vd.y; b0 += w * vc.x; b1 += w * vc.y;
                }
                #pragma unroll
                for (int j = 0; j < HDIM; j += 4) {
                    const float4 u0 = *(const float4*)(s_wd1 + (2 * l + 0) * HDIM + j);
                    const float4 u1 = *(const float4*)(s_wd1 + (2 * l + 1) * HDIM + j);
                    hbD[j + 0] += a0 * u0.x + a1 * u1.x;
                    hbD[j + 1] += a0 * u0.y + a1 * u1.y;
                    hbD[j + 2] += a0 * u0.z + a1 * u1.z;
                    hbD[j + 3] += a0 * u0.w + a1 * u1.w;
                    const float4 v0 = *(const float4*)(s_wc1 + (2 * l + 0) * HDIM + j);
                    const float4 v1 = *(const float4*)(s_wc1 + (2 * l + 1) * HDIM + j);
                    hbC[j + 0] += b0 * v0.x + b1 * v1.x;
                    hbC[j + 1] += b0 * v0.y + b1 * v1.y;
                    hbC[j + 2] += b0 * v0.z + b1 * v1.z;
                    hbC[j + 3] += b0 * v0.w + b1 * v1.w;
                }
            }

            float dotv = 0.f;
            #pragma unroll
            for (int j = 0; j < HDIM; ++j) dotv += fmaxf(hbD[j], 0.f) * s_wd2[j];
            sv = __expf(dotv) * (te - ts);

            float pr = 0.f, pg = 0.f, pb = 0.f;
            #pragma unroll
            for (int j = 0; j < HDIM; ++j) {
                const float hj = fmaxf(hbC[j], 0.f);
                pr += hj * s_wc2[3 * j + 0];
                pg += hj * s_wc2[3 * j + 1];
                pb += hj * s_wc2[3 * j + 2];
            }
            R = 1.f / (1.f + __expf(-pr));
            G = 1.f / (1.f + __expf(-pg));
            B = 1.f / (1.f + __expf(-pb));
        }

        float incl = sv;
        #pragma unroll
        for (int off = 1; off < 64; off <<= 1) {
            float t = __shfl_up(incl, off);
            if (lane >= off) incl += t;
        }
        const float e = carry + (incl - sv);
        const float w = valid ? (1.f - __expf(-sv)) * __expf(-e) : 0.f;
        accw += w; cr += w * R; cg += w * G; cb += w * B;
        carry += __shfl(incl, 63);
    }

    #pragma unroll
    for (int off = 32; off > 0; off >>= 1) {
        accw += __shfl_down(accw, off);
        cr   += __shfl_down(cr, off);
        cg   += __shfl_down(cg, off);
        cb   += __shfl_down(cb, off);
    }

    if (lane == 0) {
        const float bgw = 1.f - accw;
        out[0 * HW_NRAYS + r] = clamp01f(cr + bgw);
        out[1 * HW_NRAYS + r] = clamp01f(cg + bgw);
        out[2 * HW_NRAYS + r] = clamp01f(cb + bgw);
        out[3 * HW_NRAYS + r] = clamp01f(accw);
    }
}

extern "C" void kernel_launch(void* const* d_in, const int* in_sizes, int n_in,
                              void* d_out, int out_size, void* d_ws, size_t ws_size,
                              hipStream_t stream) {
    const float* rays_o        = (const float*)d_in[0];
    const float* rays_d        = (const float*)d_in[1];
    const float* t_starts      = (const float*)d_in[2];
    const float* t_ends        = (const float*)d_in[3];
    const int*   ray_indices   = (const int*)d_in[4];
    const float* table_density = (const float*)d_in[5];
    const float* table_color   = (const float*)d_in[6];
    const float* w_d1          = (const float*)d_in[7];
    const float* w_d2          = (const float*)d_in[8];
    const float* w_c1          = (const float*)d_in[9];
    const float* w_c2          = (const float*)d_in[10];
    float* outp = (float*)d_out;

    if (ws_size >= WS_TAB_BYTES) {
        uint2* ws_tab = (uint2*)d_ws;
        hipLaunchKernelGGL(ngp_pack_tables, dim3(1024), dim3(256), 0, stream,
                           (const float2*)table_density, (const float2*)table_color, ws_tab);
        hipLaunchKernelGGL(ngp_render_fast, dim3(HW_NRAYS / 4), dim3(256), 0, stream,
                           rays_o, rays_d, t_starts, t_ends, ray_indices, ws_tab,
                           w_d1, w_d2, w_c1, w_c2, outp);
    } else {
        hipLaunchKernelGGL(ngp_render_ref, dim3(HW_NRAYS), dim3(64), 0, stream,
                           rays_o, rays_d, t_starts, t_ends, ray_indices,
                           table_density, table_color,
                           w_d1, w_d2, w_c1, w_c2, outp);
    }
}